// Round 7
// baseline (188.618 us; speedup 1.0000x reference)
//
#include <hip/hip_runtime.h>
#include <math.h>

#define LAMBDA_DAG 0.5f
#define SCAN_U 8
#define TILEN (256 * SCAN_U)   // float4 per block-tile (2048) = 32 KB
#define LBUF_CAP 2048          // per-block LDS edge buffer

typedef float f4v __attribute__((ext_vector_type(4)));

// Inline fallback (only reachable in the non-fused path, where pT is ready).
__device__ __forceinline__ void process_edge_inline(
        unsigned e, const float* __restrict__ pT,
        float* __restrict__ per_term, float* __restrict__ npar, int B, int C) {
    const unsigned ui = e / (unsigned)C;
    const int i = (int)ui;
    const int j = (int)(e - ui * (unsigned)C);
    float s = 0.f;
    for (int b = 0; b < B; ++b) {
        float df = fmaxf(pT[(size_t)i * B + b] - pT[(size_t)j * B + b], 0.f);
        s += df * df;
    }
    atomicAdd(&per_term[i], s);
    atomicAdd(&npar[i], 1.f);
}

// Round-5 A/B verdict: nontemporal loads ~2x faster per byte than cached
// (poison fill leaves L3 full of dirty lines; allocating reads force victim
// writebacks). All streamed-once data (dag, logits, labels) uses nt.
__device__ __forceinline__ f4v ld4nt(const float* p) {
    return __builtin_nontemporal_load((const f4v*)p);
}
__device__ __forceinline__ float ld1nt(const float* p) {
    return __builtin_nontemporal_load(p);
}

// push edge: LDS buffer first; overflow goes straight to the global pool.
// In fused mode pool_cap >= C*C so the pool can NEVER overflow; inline_ok
// is only used in the non-fused path (pT ready).
#define PUSH_EDGE(E)                                                        \
    {                                                                       \
        const int pos = atomicAdd(&lcnt, 1);                                \
        if (pos < LBUF_CAP) lbuf[pos] = (E);                                \
        else {                                                              \
            const int gp = atomicAdd(ecnt, 1);                              \
            if (gp < pool_cap) elist[gp] = (E);                             \
            else if (inline_ok) process_edge_inline((E), pT, per_term,      \
                                                    npar, B, C);            \
        }                                                                   \
    }

#define PROCESS_TILE(R, tbase)                                              \
    {                                                                       \
        unsigned any = 0u;                                                  \
        _Pragma("unroll")                                                   \
        for (int u = 0; u < SCAN_U; ++u)                                    \
            any |= __float_as_uint(R[u][0]) | __float_as_uint(R[u][1]) |    \
                   __float_as_uint(R[u][2]) | __float_as_uint(R[u][3]);     \
        if (any != 0u) {                                                    \
            _Pragma("unroll")                                               \
            for (int u = 0; u < SCAN_U; ++u) {                              \
                _Pragma("unroll")                                           \
                for (int k = 0; k < 4; ++k) {                               \
                    if (R[u][k] > 0.f) {                                    \
                        const unsigned e = (unsigned)(((tbase) + u * 256 +  \
                                           (int)threadIdx.x) * 4 + k);      \
                        PUSH_EDGE(e);                                       \
                    }                                                       \
                }                                                           \
            }                                                               \
        }                                                                   \
    }

// ---- Fused kernel: blocks [0,nbA) = probs/BCE/zeroing; rest = dag scan -----
__global__ void __launch_bounds__(256) k_main(
        const float* __restrict__ logits,
        const float* __restrict__ labels,
        const float* __restrict__ dag,
        float* __restrict__ pT,        // [C*B] transposed probs
        float* __restrict__ bce_part,  // [nbA]
        float* __restrict__ per_term,  // [C] zeroed by probs blocks
        float* __restrict__ npar,      // [C] zeroed by probs blocks
        unsigned* __restrict__ elist,  // contiguous global edge pool
        int* __restrict__ ecnt,        // pool counter (pre-zeroed via memset)
        int pool_cap, int inline_ok,
        int tb, int te,                // tile range for the scan part
        int sbN,                       // scan blocks in this launch
        int do_tails,
        int nbAx, int nbAy, int B, int C) {
    const int nbA = nbAx * nbAy;
    const int bid = blockIdx.x;
    const int tid = threadIdx.x;

    __shared__ float tile[64][17];
    __shared__ float sred[256];
    __shared__ unsigned lbuf[LBUF_CAP];
    __shared__ int lcnt;

    if (bid < nbA) {
        // ---------------- probs + BCE + zero accumulators ------------------
        for (int i = bid * 256 + tid; i < C; i += nbA * 256) {
            per_term[i] = 0.f;
            npar[i] = 0.f;
        }
        const int bx = bid % nbAx, by = bid / nbAx;
        const int c0 = bx * 64;
        const int b0 = by * 16;
        const int rows = (B - b0 < 16) ? (B - b0) : 16;
        const int lc = tid & 63;
        const int c  = c0 + lc;
        const bool valid = (c < C);
        float acc = 0.f;
        if (rows > 0) {
            for (int r = tid >> 6; r < rows; r += 4) {
                const int b = b0 + r;
                float l = 0.f, y = 0.f;
                if (valid) {
                    l = ld1nt(&logits[(size_t)b * C + c]);
                    y = ld1nt(&labels[(size_t)b * C + c]);
                    // logaddexp(0,l) = max(l,0) + log1p(exp(-|l|))
                    acc += fmaxf(l, 0.f) + log1pf(expf(-fabsf(l))) - l * y;
                }
                tile[lc][r] = 1.f / (1.f + expf(-l));
            }
        }
        __syncthreads();
        if (rows > 0) {
            if ((rows & 3) == 0) {
                const int r4 = rows >> 2;
                const int tot = 64 * r4;
                for (int t = tid; t < tot; t += 256) {
                    const int row = t / r4;
                    const int q = t - row * r4;
                    const int c2 = c0 + row;
                    if (c2 < C) {
                        float4 v;
                        v.x = tile[row][q * 4 + 0];
                        v.y = tile[row][q * 4 + 1];
                        v.z = tile[row][q * 4 + 2];
                        v.w = tile[row][q * 4 + 3];
                        *(float4*)(pT + (size_t)c2 * B + b0 + q * 4) = v;
                    }
                }
            } else {
                const int tot = 64 * rows;
                for (int t = tid; t < tot; t += 256) {
                    const int row = t / rows;
                    const int r = t - row * rows;
                    const int c2 = c0 + row;
                    if (c2 < C) pT[(size_t)c2 * B + b0 + r] = tile[row][r];
                }
            }
        }
        sred[tid] = acc;
        __syncthreads();
        for (int s = 128; s > 0; s >>= 1) {
            if (tid < s) sred[tid] += sred[tid + s];
            __syncthreads();
        }
        if (tid == 0) bce_part[bid] = sred[0];
        return;
    }

    // ---------------- dag scan & compact (all-nt, pipelined) ---------------
    const int lsb = bid - nbA;          // local scan block index [0, sbN)
    if (tid == 0) lcnt = 0;
    __syncthreads();

    const int N  = C * C;
    const int N4 = N >> 2;
    const int NT = N4 / TILEN;
    const int span = (te > tb) ? ((te - tb) + sbN - 1) / sbN : 0;
    const int t0 = tb + lsb * span;
    const int t1 = (t0 + span < te) ? (t0 + span) : te;

    if (t0 < t1) {
        const float* p = dag + ((size_t)t0 * TILEN + tid) * 4;
        f4v a[SCAN_U], b[SCAN_U];
#pragma unroll
        for (int u = 0; u < SCAN_U; ++u) a[u] = ld4nt(p + u * 1024);
        for (int t = t0; t < t1; ++t) {
            const bool last = (t + 1 == t1);
            if (!last) {
#pragma unroll
                for (int u = 0; u < SCAN_U; ++u)
                    b[u] = ld4nt(p + TILEN * 4 + u * 1024);
            }
            PROCESS_TILE(a, t * TILEN);
            if (!last) {
#pragma unroll
                for (int u = 0; u < SCAN_U; ++u) a[u] = b[u];
            }
            p += TILEN * 4;
        }
    }

    if (do_tails) {
        // float4 tail (N4 % TILEN)
        for (int q = NT * TILEN + lsb * 256 + tid; q < N4; q += sbN * 256) {
            f4v d = ld4nt(dag + (size_t)q * 4);
#pragma unroll
            for (int k = 0; k < 4; ++k) {
                if (d[k] > 0.f) {
                    const unsigned e = (unsigned)(q * 4 + k);
                    PUSH_EDGE(e);
                }
            }
        }
        // scalar tail (N % 4)
        for (int e = (N4 << 2) + lsb * 256 + tid; e < N; e += sbN * 256) {
            if (dag[e] > 0.f) PUSH_EDGE((unsigned)e);
        }
    }

    // Flush LDS buffer to the contiguous pool: ONE atomicAdd per block.
    __syncthreads();
    __shared__ int gbase;
    const int n  = lcnt;
    const int nl = (n < LBUF_CAP) ? n : LBUF_CAP;
    if (tid == 0) gbase = atomicAdd(ecnt, nl);
    __syncthreads();
    const int gb = gbase;
    for (int t = tid; t < nl; t += 256) {
        const int gp = gb + t;
        if (gp < pool_cap) elist[gp] = lbuf[t];
        else if (inline_ok) process_edge_inline(lbuf[t], pT, per_term,
                                                npar, B, C);
    }
}

// ---- Edge processing: grid-stride waves over the contiguous pool -----------
// lane = batch index: pT row reads are 64 lanes x 4B = 256B, L2-resident.
__global__ void __launch_bounds__(256) k_edges(
        const float* __restrict__ pT,
        const unsigned* __restrict__ elist,
        const int* __restrict__ ecnt, int pool_cap,
        float* __restrict__ per_term,
        float* __restrict__ npar,
        int B, int C) {
    int n = *ecnt;
    if (n > pool_cap) n = pool_cap;   // overflow was handled inline
    const int lane = threadIdx.x & 63;
    const int wid  = (blockIdx.x * blockDim.x + threadIdx.x) >> 6;
    const int nw   = (gridDim.x * blockDim.x) >> 6;

    for (int t = wid; t < n; t += nw) {
        const unsigned e = elist[t];
        const unsigned ui = e / (unsigned)C;
        const int i = (int)ui;
        const int j = (int)(e - ui * (unsigned)C);
        const float* pi = pT + (size_t)i * B;
        const float* pj = pT + (size_t)j * B;
        float s = 0.f;
        for (int b = lane; b < B; b += 64) {
            float df = fmaxf(pi[b] - pj[b], 0.f);
            s += df * df;
        }
#pragma unroll
        for (int off = 32; off > 0; off >>= 1) s += __shfl_down(s, off, 64);
        if (lane == 0) {
            atomicAdd(&per_term[i], s);
            atomicAdd(&npar[i], 1.f);
        }
    }
}

// ---- Final scalar reduction ------------------------------------------------
__global__ void k_final(const float* __restrict__ per_term,
                        const float* __restrict__ npar,
                        const float* __restrict__ bce_part, int nb,
                        float* __restrict__ out, int B, int C) {
    float bs = 0.f, ps = 0.f, es = 0.f;
    for (int k = threadIdx.x; k < nb; k += blockDim.x) bs += bce_part[k];
    for (int i = threadIdx.x; i < C; i += blockDim.x) {
        float np = npar[i];
        es += np;
        if (np > 0.f) ps += per_term[i] / ((float)B * np);
    }
    __shared__ float s1[256], s2[256], s3[256];
    s1[threadIdx.x] = bs;
    s2[threadIdx.x] = ps;
    s3[threadIdx.x] = es;
    __syncthreads();
    for (int s = blockDim.x >> 1; s > 0; s >>= 1) {
        if (threadIdx.x < s) {
            s1[threadIdx.x] += s1[threadIdx.x + s];
            s2[threadIdx.x] += s2[threadIdx.x + s];
            s3[threadIdx.x] += s3[threadIdx.x + s];
        }
        __syncthreads();
    }
    if (threadIdx.x == 0) {
        float penalty = (s3[0] > 0.f) ? (s2[0] / s3[0]) : 0.f;
        out[0] = s1[0] / (float)(B * C) + LAMBDA_DAG * penalty;
    }
}

extern "C" void kernel_launch(void* const* d_in, const int* in_sizes, int n_in,
                              void* d_out, int out_size, void* d_ws, size_t ws_size,
                              hipStream_t stream) {
    const float* logits = (const float*)d_in[0];
    const float* labels = (const float*)d_in[1];
    const float* dag    = (const float*)d_in[2];
    float* out = (float*)d_out;

    const int C = (int)(sqrt((double)in_sizes[2]) + 0.5);
    const int B = in_sizes[0] / C;

    const int gridAx = (C + 63) / 64;
    const int gridAy = (B + 15) / 16;
    const int nbA = gridAx * gridAy;

    const int N4 = (C * C) >> 2;
    const int NT = N4 / TILEN;                     // 3051 full tiles at C=5000
    const int scanB = 1024;                        // span 3 -> real pipelining

    float* ws       = (float*)d_ws;
    float* pT       = ws;                          // C*B
    float* per_term = pT + (size_t)C * B;          // C
    float* nparw    = per_term + C;                // C
    float* bce_part = nparw + C;                   // nbA
    int*   ecnt     = (int*)(bce_part + nbA);      // 1
    unsigned* elist = (unsigned*)(ecnt + 1);       // pool

    const size_t base_words = (size_t)C * B + 2 * (size_t)C + nbA + 1;
    const size_t ws_words = ws_size / 4;
    long long avail = (ws_words > base_words)
                    ? (long long)(ws_words - base_words) : 0;
    const long long need = (long long)C * (long long)C;  // absolute worst case

    int fused, inline_ok, pool_cap;
    if (avail >= need) {
        fused = 1; inline_ok = 0;
        pool_cap = (int)((need < 0x7fffffffLL) ? need : 0x7fffffffLL);
    } else {
        fused = 0; inline_ok = 1;                  // probs first, inline overflow
        pool_cap = (int)((avail < 0) ? 0
                   : (avail > 0x7fffffffLL ? 0x7fffffffLL : avail));
    }

    hipMemsetAsync(ecnt, 0, sizeof(int), stream);

    if (fused) {
        // Single fused launch: probs blocks + all-nt pipelined scan + tails.
        // Pool overflow is impossible (pool_cap >= C*C), so the scan part
        // never touches pT -> no ordering hazard with the probs blocks.
        k_main<<<nbA + scanB, 256, 0, stream>>>(
            logits, labels, dag, pT, bce_part, per_term, nparw,
            elist, ecnt, pool_cap, 0,
            0, NT, scanB, 1, gridAx, gridAy, B, C);
    } else {
        k_main<<<nbA, 256, 0, stream>>>(           // probs only
            logits, labels, dag, pT, bce_part, per_term, nparw,
            elist, ecnt, pool_cap, 0,
            0, 0, 1, 0, gridAx, gridAy, B, C);
        k_main<<<scanB, 256, 0, stream>>>(         // scan, inline overflow ok
            logits, labels, dag, pT, bce_part, per_term, nparw,
            elist, ecnt, pool_cap, inline_ok,
            0, NT, scanB, 1, 0, 0, B, C);
    }

    k_edges<<<256, 256, 0, stream>>>(pT, elist, ecnt, pool_cap,
                                     per_term, nparw, B, C);
    k_final<<<1, 256, 0, stream>>>(per_term, nparw, bce_part, nbA, out, B, C);
}